// Round 3
// baseline (1199.268 us; speedup 1.0000x reference)
//
#include <hip/hip_runtime.h>

#define E_EXP 4
#define D_MODEL 1024
#define B_BATCH 4
#define S_SEQ 4096
#define NTOK (B_BATCH*S_SEQ)   // 16384
#define CHUNK 32
#define NCHUNK (S_SEQ/CHUNK)   // 128

typedef float f4 __attribute__((ext_vector_type(4)));
typedef float f32x4 __attribute__((ext_vector_type(4)));
typedef short bf16x8 __attribute__((ext_vector_type(8)));

__device__ __forceinline__ unsigned short f2b(float f){
  union{float f;unsigned u;}v; v.f=f;
  unsigned r = v.u + 0x7fffu + ((v.u>>16)&1u);
  return (unsigned short)(r>>16);
}
__device__ __forceinline__ float b2f_lo(unsigned v){ union{unsigned u;float f;}x; x.u=v<<16; return x.f; }
__device__ __forceinline__ float b2f_hi(unsigned v){ union{unsigned u;float f;}x; x.u=v&0xffff0000u; return x.f; }

__device__ __forceinline__ void gload_lds16(const void* g, void* l){
  __builtin_amdgcn_global_load_lds(
      (const __attribute__((address_space(1))) void*)g,
      (__attribute__((address_space(3))) void*)l, 16, 0, 0);
}

// ---------------- fp32 -> bf16 conversion (flat) ----------------
__global__ __launch_bounds__(256) void cvt_bf16(const float* __restrict__ src,
                                                unsigned short* __restrict__ dst)
{
  size_t i = ((size_t)blockIdx.x*256 + threadIdx.x)*4;
  f4 v = *(const f4*)(src + i);
  ushort4 o; o.x=f2b(v[0]); o.y=f2b(v[1]); o.z=f2b(v[2]); o.w=f2b(v[3]);
  *(ushort4*)(dst + i) = o;
}

// Wg/Wv/Wd expert slices -> Wcat[le][3][D][D] bf16
__global__ __launch_bounds__(256) void cvt_w3(const float* __restrict__ Wg,
                                              const float* __restrict__ Wv,
                                              const float* __restrict__ Wd,
                                              unsigned short* __restrict__ Wcat,
                                              int e0)
{
  const size_t DD = (size_t)D_MODEL*D_MODEL;   // 2^20
  size_t i4 = ((size_t)blockIdx.x*256 + threadIdx.x)*4;
  size_t le3m = i4 >> 20;          // / DD
  size_t rem  = i4 & (DD-1);
  int mat = (int)(le3m % 3);
  int le  = (int)(le3m / 3);
  const float* src = (mat==0 ? Wg : (mat==1 ? Wv : Wd)) + (size_t)(e0+le)*DD + rem;
  f4 v = *(const f4*)src;
  ushort4 o; o.x=f2b(v[0]); o.y=f2b(v[1]); o.z=f2b(v[2]); o.w=f2b(v[3]);
  *(ushort4*)(Wcat + le3m*DD + rem) = o;
}

// ---------------- router: top-2 softmax gate weights per token ----------------
__global__ __launch_bounds__(256) void router_kernel(
    const float* __restrict__ x, const float* __restrict__ Wgate,
    float* __restrict__ wtok)
{
  int gtid = blockIdx.x*256 + threadIdx.x;
  int tok  = gtid >> 6;
  int lane = threadIdx.x & 63;
  const float* xr = x + (size_t)tok * D_MODEL;
  float acc0=0.f,acc1=0.f,acc2=0.f,acc3=0.f;
  for (int k=lane;k<D_MODEL;k+=64){
    float xv = xr[k];
    acc0 += xv*Wgate[0*D_MODEL+k];
    acc1 += xv*Wgate[1*D_MODEL+k];
    acc2 += xv*Wgate[2*D_MODEL+k];
    acc3 += xv*Wgate[3*D_MODEL+k];
  }
  #pragma unroll
  for (int off=32;off>0;off>>=1){
    acc0 += __shfl_down(acc0,off);
    acc1 += __shfl_down(acc1,off);
    acc2 += __shfl_down(acc2,off);
    acc3 += __shfl_down(acc3,off);
  }
  if (lane==0){
    float l[4]={acc0,acc1,acc2,acc3};
    int i1=0;
    #pragma unroll
    for(int e=1;e<4;e++) if (l[e]>l[i1]) i1=e;
    int i2=-1;
    #pragma unroll
    for(int e=0;e<4;e++){ if(e==i1) continue; if(i2<0||l[e]>l[i2]) i2=e; }
    float ex = __expf(l[i2]-l[i1]);
    float w1 = 1.f/(1.f+ex);
    float w2 = ex/(1.f+ex);
    float w[4]={0.f,0.f,0.f,0.f};
    w[i1]=w1; w[i2]=w2;
    float* wp = wtok + (size_t)tok*E_EXP;
    wp[0]=w[0]; wp[1]=w[1]; wp[2]=w[2]; wp[3]=w[3];
  }
}

// ---------------- fused 256x256 bf16 MFMA GEMM: g,v,d in one block + act epilogue ----
// Per block: 3 K-loops (mats g,v,d) over the same (m,n) tile. Round-1 WINDOW2
// schedule (best measured). Epilogue: xs = sig(g+bg)*tanh(v+bv) (g via bf16
// round, numerically identical to prior g-plane store), aa = 0.001+0.998*sig(d+bd).
// Output: ONE u32 plane per expert: lo16 = xs bf16, hi16 = aa bf16.
#define BM2 256
#define BN2 256
#define BK2 64
#define NT2 (D_MODEL/BK2)   // 16

__global__ __launch_bounds__(512) void gemm_fused(
    const unsigned short* __restrict__ A,     // xbf [NTOK][D]
    const unsigned short* __restrict__ Wcat,  // [G][3][D][D] bf16
    const float* __restrict__ bg, const float* __restrict__ bv, const float* __restrict__ bd,
    unsigned* __restrict__ gxa,               // [G][NTOK][D] u32 (xs | aa<<16)
    int e0)
{
  __shared__ unsigned short sA[2][BM2][BK2];  // 64 KiB
  __shared__ unsigned short sB[2][BN2][BK2];  // 64 KiB
  const size_t DD = (size_t)D_MODEL*D_MODEL;
  const size_t ND = (size_t)NTOK*D_MODEL;

  const int le    = blockIdx.z;
  const int mbase = blockIdx.x*BM2;
  const int nbase = blockIdx.y*BN2;           // y in 0..3
  const int e     = e0 + le;

  const int tid  = threadIdx.x;
  const int wave = tid>>6, lane = tid&63;
  const int wm = wave>>2, wn = wave&3;        // 2M x 4N wave grid; per-wave out 128x64
  const int l15 = lane&15;
  const int l8  = lane>>3;
  const int lc  = (lane&7) ^ l8;              // pre-swizzled logical chunk for staging

  const unsigned short* gA  = A + (size_t)(mbase + wave*8 + l8)*D_MODEL + lc*8;
  const int bBw = (wave>>1)*64 + (wave&1)*8;  // per-wave B dest row base
  const unsigned short* gB0 = Wcat + (size_t)le*3*DD + (size_t)(nbase + bBw + l8)*D_MODEL + lc*8;
  const unsigned short* gB  = gB0;

  // fragment read addressing (swizzle-aware)
  const int arow = wm*128 + l15;
  const int brow = wn*64  + l15;
  const int ach0 = (((lane>>4)    ) ^ (lane&7))*8;   // kk=0 phys chunk, ushort off
  const int ach1 = (((lane>>4) + 4) ^ (lane&7))*8;   // kk=1

  f32x4 acc[8][4];
  bf16x8 af[4][2], bfv[2][2];
  unsigned pk[8][4][2];                        // packed bf16 pairs (rows 2j,2j+1)

#define STAGE_A2(slot,t,mh) do{ \
  gload_lds16(gA + (size_t)((mh)*64)*D_MODEL     + (t)*BK2, &sA[slot][(mh)*64 + wave*8][0]); \
  gload_lds16(gA + (size_t)(128+(mh)*64)*D_MODEL + (t)*BK2, &sA[slot][128+(mh)*64 + wave*8][0]); \
}while(0)
#define STAGE_B2(slot,t,nh) do{ \
  gload_lds16(gB + (size_t)((nh)*32)*D_MODEL    + (t)*BK2, &sB[slot][bBw + (nh)*32][0]); \
  gload_lds16(gB + (size_t)((nh)*32+16)*D_MODEL + (t)*BK2, &sB[slot][bBw + (nh)*32 + 16][0]); \
}while(0)
#define LOAD_A2(slot,mh) do{ \
  _Pragma("unroll") for (int _m=0;_m<4;++_m){ \
    af[_m][0] = *(const bf16x8*)&sA[slot][arow + ((mh)*4+_m)*16][ach0]; \
    af[_m][1] = *(const bf16x8*)&sA[slot][arow + ((mh)*4+_m)*16][ach1]; \
  } \
}while(0)
#define LOAD_B2(slot,nh) do{ \
  _Pragma("unroll") for (int _n=0;_n<2;++_n){ \
    bfv[_n][0] = *(const bf16x8*)&sB[slot][brow + ((nh)*2+_n)*16][ach0]; \
    bfv[_n][1] = *(const bf16x8*)&sB[slot][brow + ((nh)*2+_n)*16][ach1]; \
  } \
}while(0)
#define MQ2(mh,nh) do{ \
  _Pragma("unroll") for (int _m=0;_m<4;++_m) \
  _Pragma("unroll") for (int _n=0;_n<2;++_n) \
  _Pragma("unroll") for (int _k=0;_k<2;++_k) \
    acc[(mh)*4+_m][(nh)*2+_n] = __builtin_amdgcn_mfma_f32_16x16x32_bf16( \
        af[_m][_k], bfv[_n][_k], acc[(mh)*4+_m][(nh)*2+_n], 0,0,0); \
}while(0)
#define KC_LGKM0  asm volatile("s_waitcnt lgkmcnt(0)" ::: "memory")
#define KC_LGKM8  asm volatile("s_waitcnt lgkmcnt(8)" ::: "memory")
#define KC_VM4    asm volatile("s_waitcnt vmcnt(4)" ::: "memory")
#define BAR       __builtin_amdgcn_s_barrier()
#define PRIO1     __builtin_amdgcn_s_setprio(1)
#define PRIO0     __builtin_amdgcn_s_setprio(0)

// Round-1 verified window: quadrant order (0,0),(0,1),(1,1),(1,0); stages:
// ph0: A1+B0(T1)->oslot; ph2: A0(T2)->slot; ph3: B1(T2)->slot + vmcnt(4)
#define WINDOW2(slot,oslot,T1,T2) do{ \
  LOAD_A2(slot,0); LOAD_B2(slot,0); \
  STAGE_A2(oslot,T1,1); STAGE_B2(oslot,T1,0); \
  KC_LGKM8; BAR; KC_LGKM0; \
  PRIO1; MQ2(0,0); PRIO0; BAR; \
  LOAD_B2(slot,1); \
  BAR; KC_LGKM0; \
  PRIO1; MQ2(0,1); PRIO0; BAR; \
  LOAD_A2(slot,1); \
  STAGE_A2(slot,T2,0); \
  BAR; KC_LGKM0; \
  PRIO1; MQ2(1,1); PRIO0; BAR; \
  LOAD_B2(slot,0); \
  STAGE_B2(slot,T2,1); \
  KC_VM4; BAR; KC_LGKM0; \
  PRIO1; MQ2(1,0); PRIO0; BAR; \
}while(0)

#define RUN_MAT() do{ \
  _Pragma("unroll") for (int _i=0;_i<8;_i++) \
    _Pragma("unroll") for (int _j=0;_j<4;_j++) acc[_i][_j] = 0; \
  STAGE_A2(0,0,0); STAGE_A2(0,0,1); STAGE_B2(0,0,0); STAGE_B2(0,0,1); \
  STAGE_A2(1,1,0); STAGE_B2(1,1,1); \
  KC_VM4; BAR; \
  for (int tp=0; tp<NT2/2; ++tp){ \
    int ta = 2*tp+1; \
    int tb = 2*tp+2; if (tb>=NT2) tb -= NT2; \
    int tc = 2*tp+3; if (tc>=NT2) tc -= NT2; \
    WINDOW2(0,1,ta,tb); \
    WINDOW2(1,0,tb,tc); \
  } \
  asm volatile("s_waitcnt vmcnt(0)" ::: "memory"); \
}while(0)

  const int ne = nbase + wn*64;
  const int me = mbase + wm*128;

  // ---- mat 0: g -> pack to bf16 pairs (numerically == prior bf16 g-plane) ----
  RUN_MAT();
  #pragma unroll
  for (int mi=0;mi<8;mi++)
    #pragma unroll
    for (int ni=0;ni<4;ni++)
      #pragma unroll
      for (int j=0;j<2;j++)
        pk[mi][ni][j] = (unsigned)f2b(acc[mi][ni][2*j]) | ((unsigned)f2b(acc[mi][ni][2*j+1])<<16);

  // ---- mat 1: v -> xs = sigmoid(g+bg)*tanh(v+bv), packed in place ----
  gB = gB0 + DD;
  RUN_MAT();
  {
    float bgv[4], bvv[4];
    #pragma unroll
    for (int ni=0;ni<4;ni++){
      int n = ne + ni*16 + l15;
      bgv[ni] = bg[(size_t)e*D_MODEL + n];
      bvv[ni] = bv[(size_t)e*D_MODEL + n];
    }
    #pragma unroll
    for (int mi=0;mi<8;mi++)
      #pragma unroll
      for (int ni=0;ni<4;ni++)
        #pragma unroll
        for (int j=0;j<2;j++){
          unsigned w = pk[mi][ni][j];
          float g0 = b2f_lo(w)+bgv[ni], g1 = b2f_hi(w)+bgv[ni];
          float v0 = acc[mi][ni][2*j]+bvv[ni], v1 = acc[mi][ni][2*j+1]+bvv[ni];
          float x0 = (1.f/(1.f+__expf(-g0))) * (1.f - 2.f/(__expf(2.f*v0)+1.f));
          float x1 = (1.f/(1.f+__expf(-g1))) * (1.f - 2.f/(__expf(2.f*v1)+1.f));
          pk[mi][ni][j] = (unsigned)f2b(x0) | ((unsigned)f2b(x1)<<16);
        }
  }

  // ---- mat 2: d -> aa = 0.001+0.998*sigmoid(d+bd); store xs|aa u32 plane ----
  gB = gB0 + 2*DD;
  RUN_MAT();
  {
    float bdv[4];
    #pragma unroll
    for (int ni=0;ni<4;ni++) bdv[ni] = bd[(size_t)e*D_MODEL + ne + ni*16 + l15];
    unsigned* outp = gxa + (size_t)le*ND;
    #pragma unroll
    for (int mi=0;mi<8;mi++){
      #pragma unroll
      for (int j=0;j<2;j++){
        int m0 = me + mi*16 + (lane>>4)*4 + 2*j;
        size_t ro0 = (size_t)m0*D_MODEL;
        size_t ro1 = ro0 + D_MODEL;
        #pragma unroll
        for (int ni=0;ni<4;ni++){
          int n = ne + ni*16 + l15;
          float d0v = acc[mi][ni][2*j]   + bdv[ni];
          float d1v = acc[mi][ni][2*j+1] + bdv[ni];
          float a0 = 0.001f + 0.998f/(1.f+__expf(-d0v));
          float a1 = 0.001f + 0.998f/(1.f+__expf(-d1v));
          unsigned w = pk[mi][ni][j];
          outp[ro0+n] = (w & 0xffffu) | ((unsigned)f2b(a0)<<16);
          outp[ro1+n] = (w >> 16)     | ((unsigned)f2b(a1)<<16);
        }
      }
    }
  }
}

// ---------------- pass 1 (lean): local chunk scan over packed xs|aa ----------------
__global__ __launch_bounds__(512) void scan_pass1(
    const unsigned* __restrict__ gxa,   // [G][NTOK][D] u32
    float* __restrict__ P, float* __restrict__ U)
{
  const size_t ND = (size_t)NTOK*D_MODEL;
  int blk = blockIdx.x;
  int c  = blk % NCHUNK;
  int b  = (blk / NCHUNK) % B_BATCH;
  int le = blk / (NCHUNK*B_BATCH);
  int d0 = threadIdx.x*2;

  const unsigned* gp = gxa + (size_t)le*ND;
  size_t base = (((size_t)b)*S_SEQ + (size_t)c*CHUNK)*D_MODEL + d0;
  float h0=0.f,h1=0.f,p0=1.f,p1=1.f;
  for (int t=0;t<CHUNK;t++){
    uint2 w = *(const uint2*)(gp + base);
    float x0 = b2f_lo(w.x), a0 = b2f_hi(w.x);
    float x1 = b2f_lo(w.y), a1 = b2f_hi(w.y);
    h0 = a0*h0 + x0; h1 = a1*h1 + x1;
    p0 *= a0; p1 *= a1;
    base += D_MODEL;
  }
  size_t sidx = (((size_t)(le*B_BATCH + b))*NCHUNK + c)*D_MODEL + d0;
  P[sidx]=p0; P[sidx+1]=p1;
  U[sidx]=h0; U[sidx+1]=h1;
}

// ---------------- pass 2: sequential combine over chunks -> Hinit per chunk ----------------
__global__ __launch_bounds__(256) void scan_pass2(
    const float* __restrict__ P, const float* __restrict__ U, float* __restrict__ Hinit)
{
  int ch = blockIdx.x*256 + threadIdx.x;
  int d  = ch & (D_MODEL-1);
  int eb = ch >> 10;
  size_t base = (size_t)eb*NCHUNK*D_MODEL + d;
  float H=0.f;
  for (int c=0;c<NCHUNK;c++){
    size_t idx = base + (size_t)c*D_MODEL;
    Hinit[idx] = H;
    H = P[idx]*H + U[idx];
  }
}

// ---------------- pass 3: re-scan + fused top-2 weighted combine ----------------
template<int G, int FIRST>
__global__ __launch_bounds__(512) void scan_pass3(
    const unsigned* __restrict__ gxa,   // [G][NTOK][D] u32 (xs | aa<<16)
    const float* __restrict__ Hinit, const float* __restrict__ wtok,
    float* __restrict__ out, int e0)
{
  const size_t ND = (size_t)NTOK*D_MODEL;
  int blk = blockIdx.x;
  int c = blk % NCHUNK;
  int b = blk / NCHUNK;
  int d0 = threadIdx.x*2;
  float h[G][2];
  #pragma unroll
  for (int le=0; le<G; le++){
    size_t hi = (((size_t)(le*B_BATCH+b))*NCHUNK + c)*D_MODEL + d0;
    h[le][0]=Hinit[hi]; h[le][1]=Hinit[hi+1];
  }
  int s0 = c*CHUNK;
  for (int t=0;t<CHUNK;t++){
    size_t n = (size_t)b*S_SEQ + s0 + t;
    float o0=0.f, o1=0.f;
    #pragma unroll
    for (int le=0;le<G;le++){
      float w = wtok[n*E_EXP + e0 + le];
      uint2 wv = *(const uint2*)(gxa + (size_t)le*ND + n*D_MODEL + d0);
      h[le][0] = b2f_hi(wv.x)*h[le][0] + b2f_lo(wv.x);
      h[le][1] = b2f_hi(wv.y)*h[le][1] + b2f_lo(wv.y);
      o0 += w*h[le][0];
      o1 += w*h[le][1];
    }
    float* op = out + n*D_MODEL + d0;
    if (FIRST){ op[0]=o0;  op[1]=o1;  }
    else      { op[0]+=o0; op[1]+=o1; }
  }
}

extern "C" void kernel_launch(void* const* d_in, const int* in_sizes, int n_in,
                              void* d_out, int out_size, void* d_ws, size_t ws_size,
                              hipStream_t stream)
{
  const float* x     = (const float*)d_in[0];
  const float* Wg    = (const float*)d_in[1];
  const float* bg    = (const float*)d_in[2];
  const float* Wv    = (const float*)d_in[3];
  const float* bv    = (const float*)d_in[4];
  const float* Wd    = (const float*)d_in[5];
  const float* bd    = (const float*)d_in[6];
  const float* Wgate = (const float*)d_in[7];
  float* out = (float*)d_out;

  const size_t DD        = (size_t)D_MODEL*D_MODEL;
  const size_t ND        = (size_t)NTOK*D_MODEL;
  const size_t wtok_b    = (size_t)NTOK*E_EXP*4;             // 256 KiB
  const size_t xbf_b     = ND*2;                             // 32 MiB
  const size_t w_per_e   = 3*DD*2;                           // 6 MiB
  const size_t gxa_per_e = ND*4;                             // 64 MiB (u32 xs|aa)
  const size_t st_per_e  = (size_t)B_BATCH*NCHUNK*D_MODEL*4; // 2 MiB

  int G = 1;
  for (int g = 4; g >= 1; g >>= 1){
    size_t need = wtok_b + xbf_b + (size_t)g*(w_per_e + gxa_per_e + 3*st_per_e);
    if (need <= ws_size){ G = g; break; }
  }

  char* wsb = (char*)d_ws;
  size_t off = 0;
  float*          wtok = (float*)(wsb+off);          off += wtok_b;
  unsigned short* xbf  = (unsigned short*)(wsb+off); off += xbf_b;
  unsigned short* Wcat = (unsigned short*)(wsb+off); off += (size_t)G*w_per_e;
  unsigned*       gxa  = (unsigned*)(wsb+off);       off += (size_t)G*gxa_per_e;
  float*          P    = (float*)(wsb+off);          off += (size_t)G*st_per_e;
  float*          U    = (float*)(wsb+off);          off += (size_t)G*st_per_e;
  float*          Hi   = (float*)(wsb+off);

  cvt_bf16<<<(unsigned)(ND/1024), 256, 0, stream>>>(x, xbf);
  router_kernel<<<NTOK/4, 256, 0, stream>>>(x, Wgate, wtok);

  for (int e0=0; e0<E_EXP; e0+=G){
    cvt_w3<<<(unsigned)((size_t)G*3*DD/1024), 256, 0, stream>>>(Wg, Wv, Wd, Wcat, e0);

    dim3 gg(NTOK/BM2, D_MODEL/BN2, G);
    gemm_fused<<<gg, 512, 0, stream>>>(xbf, Wcat, bg, bv, bd, gxa, e0);

    scan_pass1<<<G*B_BATCH*NCHUNK, 512, 0, stream>>>(gxa, P, U);
    scan_pass2<<<G*B_BATCH*D_MODEL/256, 256, 0, stream>>>(P, U, Hi);
    bool first = (e0 == 0);
    if (G==4)      scan_pass3<4,1><<<B_BATCH*NCHUNK, 512, 0, stream>>>(gxa, Hi, wtok, out, e0);
    else if (G==2){
      if (first) scan_pass3<2,1><<<B_BATCH*NCHUNK, 512, 0, stream>>>(gxa, Hi, wtok, out, e0);
      else       scan_pass3<2,0><<<B_BATCH*NCHUNK, 512, 0, stream>>>(gxa, Hi, wtok, out, e0);
    } else {
      if (first) scan_pass3<1,1><<<B_BATCH*NCHUNK, 512, 0, stream>>>(gxa, Hi, wtok, out, e0);
      else       scan_pass3<1,0><<<B_BATCH*NCHUNK, 512, 0, stream>>>(gxa, Hi, wtok, out, e0);
    }
  }
}

// Round 4
// 1198.725 us; speedup vs baseline: 1.0005x; 1.0005x over previous
//
#include <hip/hip_runtime.h>

#define E_EXP 4
#define D_MODEL 1024
#define B_BATCH 4
#define S_SEQ 4096
#define NTOK (B_BATCH*S_SEQ)   // 16384
#define CHUNK 32
#define NCHUNK (S_SEQ/CHUNK)   // 128

typedef float f4 __attribute__((ext_vector_type(4)));
typedef float f32x4 __attribute__((ext_vector_type(4)));
typedef short bf16x8 __attribute__((ext_vector_type(8)));

__device__ __forceinline__ unsigned short f2b(float f){
  union{float f;unsigned u;}v; v.f=f;
  unsigned r = v.u + 0x7fffu + ((v.u>>16)&1u);
  return (unsigned short)(r>>16);
}
__device__ __forceinline__ float b2f_lo(unsigned v){ union{unsigned u;float f;}x; x.u=v<<16; return x.f; }
__device__ __forceinline__ float b2f_hi(unsigned v){ union{unsigned u;float f;}x; x.u=v&0xffff0000u; return x.f; }

__device__ __forceinline__ void gload_lds16(const void* g, void* l){
  __builtin_amdgcn_global_load_lds(
      (const __attribute__((address_space(1))) void*)g,
      (__attribute__((address_space(3))) void*)l, 16, 0, 0);
}

// ---------------- fp32 -> bf16 conversion (flat) ----------------
__global__ __launch_bounds__(256) void cvt_bf16(const float* __restrict__ src,
                                                unsigned short* __restrict__ dst)
{
  size_t i = ((size_t)blockIdx.x*256 + threadIdx.x)*4;
  f4 v = *(const f4*)(src + i);
  ushort4 o; o.x=f2b(v[0]); o.y=f2b(v[1]); o.z=f2b(v[2]); o.w=f2b(v[3]);
  *(ushort4*)(dst + i) = o;
}

// Wg/Wv/Wd expert slices -> Wcat[le][3][D][D] bf16
__global__ __launch_bounds__(256) void cvt_w3(const float* __restrict__ Wg,
                                              const float* __restrict__ Wv,
                                              const float* __restrict__ Wd,
                                              unsigned short* __restrict__ Wcat,
                                              int e0)
{
  const size_t DD = (size_t)D_MODEL*D_MODEL;   // 2^20
  size_t i4 = ((size_t)blockIdx.x*256 + threadIdx.x)*4;
  size_t le3m = i4 >> 20;          // / DD
  size_t rem  = i4 & (DD-1);
  int mat = (int)(le3m % 3);
  int le  = (int)(le3m / 3);
  const float* src = (mat==0 ? Wg : (mat==1 ? Wv : Wd)) + (size_t)(e0+le)*DD + rem;
  f4 v = *(const f4*)src;
  ushort4 o; o.x=f2b(v[0]); o.y=f2b(v[1]); o.z=f2b(v[2]); o.w=f2b(v[3]);
  *(ushort4*)(Wcat + le3m*DD + rem) = o;
}

// ---------------- router: top-2 softmax gate weights per token ----------------
__global__ __launch_bounds__(256) void router_kernel(
    const float* __restrict__ x, const float* __restrict__ Wgate,
    float* __restrict__ wtok)
{
  int gtid = blockIdx.x*256 + threadIdx.x;
  int tok  = gtid >> 6;
  int lane = threadIdx.x & 63;
  const float* xr = x + (size_t)tok * D_MODEL;
  float acc0=0.f,acc1=0.f,acc2=0.f,acc3=0.f;
  for (int k=lane;k<D_MODEL;k+=64){
    float xv = xr[k];
    acc0 += xv*Wgate[0*D_MODEL+k];
    acc1 += xv*Wgate[1*D_MODEL+k];
    acc2 += xv*Wgate[2*D_MODEL+k];
    acc3 += xv*Wgate[3*D_MODEL+k];
  }
  #pragma unroll
  for (int off=32;off>0;off>>=1){
    acc0 += __shfl_down(acc0,off);
    acc1 += __shfl_down(acc1,off);
    acc2 += __shfl_down(acc2,off);
    acc3 += __shfl_down(acc3,off);
  }
  if (lane==0){
    float l[4]={acc0,acc1,acc2,acc3};
    int i1=0;
    #pragma unroll
    for(int e=1;e<4;e++) if (l[e]>l[i1]) i1=e;
    int i2=-1;
    #pragma unroll
    for(int e=0;e<4;e++){ if(e==i1) continue; if(i2<0||l[e]>l[i2]) i2=e; }
    float ex = __expf(l[i2]-l[i1]);
    float w1 = 1.f/(1.f+ex);
    float w2 = ex/(1.f+ex);
    float w[4]={0.f,0.f,0.f,0.f};
    w[i1]=w1; w[i2]=w2;
    float* wp = wtok + (size_t)tok*E_EXP;
    wp[0]=w[0]; wp[1]=w[1]; wp[2]=w[2]; wp[3]=w[3];
  }
}

// ---------------- fused 256x256 bf16 MFMA GEMM: g,v,d in one block + act epilogue ----
// Per block: 3 K-loops (mats g,v,d) over the same (m,n) tile. Round-1 WINDOW2
// schedule. Epilogue: xs = sig(g+bg)*tanh(v+bv) (g via bf16 round, numerically
// identical to prior g-plane store), aa = 0.001+0.998*sig(d+bd).
// Output: ONE u32 plane per expert: lo16 = xs bf16, hi16 = aa bf16.
// NOTE: __launch_bounds__(512,2) is REQUIRED — LDS (128KiB) already caps us at
// 1 block/CU (2 waves/SIMD, 512-reg/wave HW budget). Without the min-waves
// hint the allocator capped VGPRs at 128 and spilled pk[] to scratch: round-3
// counters showed +260MB FETCH / +350MB WRITE of pure spill traffic.
#define BM2 256
#define BN2 256
#define BK2 64
#define NT2 (D_MODEL/BK2)   // 16

__global__ __launch_bounds__(512, 2) void gemm_fused(
    const unsigned short* __restrict__ A,     // xbf [NTOK][D]
    const unsigned short* __restrict__ Wcat,  // [G][3][D][D] bf16
    const float* __restrict__ bg, const float* __restrict__ bv, const float* __restrict__ bd,
    unsigned* __restrict__ gxa,               // [G][NTOK][D] u32 (xs | aa<<16)
    int e0)
{
  __shared__ unsigned short sA[2][BM2][BK2];  // 64 KiB
  __shared__ unsigned short sB[2][BN2][BK2];  // 64 KiB
  const size_t DD = (size_t)D_MODEL*D_MODEL;
  const size_t ND = (size_t)NTOK*D_MODEL;

  const int le    = blockIdx.z;
  const int mbase = blockIdx.x*BM2;
  const int nbase = blockIdx.y*BN2;           // y in 0..3
  const int e     = e0 + le;

  const int tid  = threadIdx.x;
  const int wave = tid>>6, lane = tid&63;
  const int wm = wave>>2, wn = wave&3;        // 2M x 4N wave grid; per-wave out 128x64
  const int l15 = lane&15;
  const int l8  = lane>>3;
  const int lc  = (lane&7) ^ l8;              // pre-swizzled logical chunk for staging

  const unsigned short* gA  = A + (size_t)(mbase + wave*8 + l8)*D_MODEL + lc*8;
  const int bBw = (wave>>1)*64 + (wave&1)*8;  // per-wave B dest row base
  const unsigned short* gB0 = Wcat + (size_t)le*3*DD + (size_t)(nbase + bBw + l8)*D_MODEL + lc*8;
  const unsigned short* gB  = gB0;

  // fragment read addressing (swizzle-aware)
  const int arow = wm*128 + l15;
  const int brow = wn*64  + l15;
  const int ach0 = (((lane>>4)    ) ^ (lane&7))*8;   // kk=0 phys chunk, ushort off
  const int ach1 = (((lane>>4) + 4) ^ (lane&7))*8;   // kk=1

  f32x4 acc[8][4];
  bf16x8 af[4][2], bfv[2][2];
  unsigned pk[8][4][2];                        // packed bf16 pairs (rows 2j,2j+1)

#define STAGE_A2(slot,t,mh) do{ \
  gload_lds16(gA + (size_t)((mh)*64)*D_MODEL     + (t)*BK2, &sA[slot][(mh)*64 + wave*8][0]); \
  gload_lds16(gA + (size_t)(128+(mh)*64)*D_MODEL + (t)*BK2, &sA[slot][128+(mh)*64 + wave*8][0]); \
}while(0)
#define STAGE_B2(slot,t,nh) do{ \
  gload_lds16(gB + (size_t)((nh)*32)*D_MODEL    + (t)*BK2, &sB[slot][bBw + (nh)*32][0]); \
  gload_lds16(gB + (size_t)((nh)*32+16)*D_MODEL + (t)*BK2, &sB[slot][bBw + (nh)*32 + 16][0]); \
}while(0)
#define LOAD_A2(slot,mh) do{ \
  _Pragma("unroll") for (int _m=0;_m<4;++_m){ \
    af[_m][0] = *(const bf16x8*)&sA[slot][arow + ((mh)*4+_m)*16][ach0]; \
    af[_m][1] = *(const bf16x8*)&sA[slot][arow + ((mh)*4+_m)*16][ach1]; \
  } \
}while(0)
#define LOAD_B2(slot,nh) do{ \
  _Pragma("unroll") for (int _n=0;_n<2;++_n){ \
    bfv[_n][0] = *(const bf16x8*)&sB[slot][brow + ((nh)*2+_n)*16][ach0]; \
    bfv[_n][1] = *(const bf16x8*)&sB[slot][brow + ((nh)*2+_n)*16][ach1]; \
  } \
}while(0)
#define MQ2(mh,nh) do{ \
  _Pragma("unroll") for (int _m=0;_m<4;++_m) \
  _Pragma("unroll") for (int _n=0;_n<2;++_n) \
  _Pragma("unroll") for (int _k=0;_k<2;++_k) \
    acc[(mh)*4+_m][(nh)*2+_n] = __builtin_amdgcn_mfma_f32_16x16x32_bf16( \
        af[_m][_k], bfv[_n][_k], acc[(mh)*4+_m][(nh)*2+_n], 0,0,0); \
}while(0)
#define KC_LGKM0  asm volatile("s_waitcnt lgkmcnt(0)" ::: "memory")
#define KC_LGKM8  asm volatile("s_waitcnt lgkmcnt(8)" ::: "memory")
#define KC_VM4    asm volatile("s_waitcnt vmcnt(4)" ::: "memory")
#define BAR       __builtin_amdgcn_s_barrier()
#define PRIO1     __builtin_amdgcn_s_setprio(1)
#define PRIO0     __builtin_amdgcn_s_setprio(0)

// Round-1 verified window: quadrant order (0,0),(0,1),(1,1),(1,0); stages:
// ph0: A1+B0(T1)->oslot; ph2: A0(T2)->slot; ph3: B1(T2)->slot + vmcnt(4)
#define WINDOW2(slot,oslot,T1,T2) do{ \
  LOAD_A2(slot,0); LOAD_B2(slot,0); \
  STAGE_A2(oslot,T1,1); STAGE_B2(oslot,T1,0); \
  KC_LGKM8; BAR; KC_LGKM0; \
  PRIO1; MQ2(0,0); PRIO0; BAR; \
  LOAD_B2(slot,1); \
  BAR; KC_LGKM0; \
  PRIO1; MQ2(0,1); PRIO0; BAR; \
  LOAD_A2(slot,1); \
  STAGE_A2(slot,T2,0); \
  BAR; KC_LGKM0; \
  PRIO1; MQ2(1,1); PRIO0; BAR; \
  LOAD_B2(slot,0); \
  STAGE_B2(slot,T2,1); \
  KC_VM4; BAR; KC_LGKM0; \
  PRIO1; MQ2(1,0); PRIO0; BAR; \
}while(0)

#define RUN_MAT() do{ \
  _Pragma("unroll") for (int _i=0;_i<8;_i++) \
    _Pragma("unroll") for (int _j=0;_j<4;_j++) acc[_i][_j] = 0; \
  STAGE_A2(0,0,0); STAGE_A2(0,0,1); STAGE_B2(0,0,0); STAGE_B2(0,0,1); \
  STAGE_A2(1,1,0); STAGE_B2(1,1,1); \
  KC_VM4; BAR; \
  for (int tp=0; tp<NT2/2; ++tp){ \
    int ta = 2*tp+1; \
    int tb = 2*tp+2; if (tb>=NT2) tb -= NT2; \
    int tc = 2*tp+3; if (tc>=NT2) tc -= NT2; \
    WINDOW2(0,1,ta,tb); \
    WINDOW2(1,0,tb,tc); \
  } \
  asm volatile("s_waitcnt vmcnt(0)" ::: "memory"); \
}while(0)

  const int ne = nbase + wn*64;
  const int me = mbase + wm*128;

  // ---- mat 0: g -> pack to bf16 pairs (numerically == prior bf16 g-plane) ----
  RUN_MAT();
  #pragma unroll
  for (int mi=0;mi<8;mi++)
    #pragma unroll
    for (int ni=0;ni<4;ni++)
      #pragma unroll
      for (int j=0;j<2;j++)
        pk[mi][ni][j] = (unsigned)f2b(acc[mi][ni][2*j]) | ((unsigned)f2b(acc[mi][ni][2*j+1])<<16);

  // ---- mat 1: v -> xs = sigmoid(g+bg)*tanh(v+bv), packed in place ----
  gB = gB0 + DD;
  RUN_MAT();
  {
    float bgv[4], bvv[4];
    #pragma unroll
    for (int ni=0;ni<4;ni++){
      int n = ne + ni*16 + l15;
      bgv[ni] = bg[(size_t)e*D_MODEL + n];
      bvv[ni] = bv[(size_t)e*D_MODEL + n];
    }
    #pragma unroll
    for (int mi=0;mi<8;mi++)
      #pragma unroll
      for (int ni=0;ni<4;ni++)
        #pragma unroll
        for (int j=0;j<2;j++){
          unsigned w = pk[mi][ni][j];
          float g0 = b2f_lo(w)+bgv[ni], g1 = b2f_hi(w)+bgv[ni];
          float v0 = acc[mi][ni][2*j]+bvv[ni], v1 = acc[mi][ni][2*j+1]+bvv[ni];
          float x0 = (1.f/(1.f+__expf(-g0))) * (1.f - 2.f/(__expf(2.f*v0)+1.f));
          float x1 = (1.f/(1.f+__expf(-g1))) * (1.f - 2.f/(__expf(2.f*v1)+1.f));
          pk[mi][ni][j] = (unsigned)f2b(x0) | ((unsigned)f2b(x1)<<16);
        }
  }

  // ---- mat 2: d -> aa = 0.001+0.998*sigmoid(d+bd); store xs|aa u32 plane ----
  gB = gB0 + 2*DD;
  RUN_MAT();
  {
    float bdv[4];
    #pragma unroll
    for (int ni=0;ni<4;ni++) bdv[ni] = bd[(size_t)e*D_MODEL + ne + ni*16 + l15];
    unsigned* outp = gxa + (size_t)le*ND;
    #pragma unroll
    for (int mi=0;mi<8;mi++){
      #pragma unroll
      for (int j=0;j<2;j++){
        int m0 = me + mi*16 + (lane>>4)*4 + 2*j;
        size_t ro0 = (size_t)m0*D_MODEL;
        size_t ro1 = ro0 + D_MODEL;
        #pragma unroll
        for (int ni=0;ni<4;ni++){
          int n = ne + ni*16 + l15;
          float d0v = acc[mi][ni][2*j]   + bdv[ni];
          float d1v = acc[mi][ni][2*j+1] + bdv[ni];
          float a0 = 0.001f + 0.998f/(1.f+__expf(-d0v));
          float a1 = 0.001f + 0.998f/(1.f+__expf(-d1v));
          unsigned w = pk[mi][ni][j];
          outp[ro0+n] = (w & 0xffffu) | ((unsigned)f2b(a0)<<16);
          outp[ro1+n] = (w >> 16)     | ((unsigned)f2b(a1)<<16);
        }
      }
    }
  }
}

// ---------------- pass 1 (lean): local chunk scan over packed xs|aa ----------------
__global__ __launch_bounds__(512) void scan_pass1(
    const unsigned* __restrict__ gxa,   // [G][NTOK][D] u32
    float* __restrict__ P, float* __restrict__ U)
{
  const size_t ND = (size_t)NTOK*D_MODEL;
  int blk = blockIdx.x;
  int c  = blk % NCHUNK;
  int b  = (blk / NCHUNK) % B_BATCH;
  int le = blk / (NCHUNK*B_BATCH);
  int d0 = threadIdx.x*2;

  const unsigned* gp = gxa + (size_t)le*ND;
  size_t base = (((size_t)b)*S_SEQ + (size_t)c*CHUNK)*D_MODEL + d0;
  float h0=0.f,h1=0.f,p0=1.f,p1=1.f;
  for (int t=0;t<CHUNK;t++){
    uint2 w = *(const uint2*)(gp + base);
    float x0 = b2f_lo(w.x), a0 = b2f_hi(w.x);
    float x1 = b2f_lo(w.y), a1 = b2f_hi(w.y);
    h0 = a0*h0 + x0; h1 = a1*h1 + x1;
    p0 *= a0; p1 *= a1;
    base += D_MODEL;
  }
  size_t sidx = (((size_t)(le*B_BATCH + b))*NCHUNK + c)*D_MODEL + d0;
  P[sidx]=p0; P[sidx+1]=p1;
  U[sidx]=h0; U[sidx+1]=h1;
}

// ---------------- pass 2: sequential combine over chunks -> Hinit per chunk ----------------
__global__ __launch_bounds__(256) void scan_pass2(
    const float* __restrict__ P, const float* __restrict__ U, float* __restrict__ Hinit)
{
  int ch = blockIdx.x*256 + threadIdx.x;
  int d  = ch & (D_MODEL-1);
  int eb = ch >> 10;
  size_t base = (size_t)eb*NCHUNK*D_MODEL + d;
  float H=0.f;
  for (int c=0;c<NCHUNK;c++){
    size_t idx = base + (size_t)c*D_MODEL;
    Hinit[idx] = H;
    H = P[idx]*H + U[idx];
  }
}

// ---------------- pass 3: re-scan + fused top-2 weighted combine ----------------
template<int G, int FIRST>
__global__ __launch_bounds__(512) void scan_pass3(
    const unsigned* __restrict__ gxa,   // [G][NTOK][D] u32 (xs | aa<<16)
    const float* __restrict__ Hinit, const float* __restrict__ wtok,
    float* __restrict__ out, int e0)
{
  const size_t ND = (size_t)NTOK*D_MODEL;
  int blk = blockIdx.x;
  int c = blk % NCHUNK;
  int b = blk / NCHUNK;
  int d0 = threadIdx.x*2;
  float h[G][2];
  #pragma unroll
  for (int le=0; le<G; le++){
    size_t hi = (((size_t)(le*B_BATCH+b))*NCHUNK + c)*D_MODEL + d0;
    h[le][0]=Hinit[hi]; h[le][1]=Hinit[hi+1];
  }
  int s0 = c*CHUNK;
  for (int t=0;t<CHUNK;t++){
    size_t n = (size_t)b*S_SEQ + s0 + t;
    float o0=0.f, o1=0.f;
    #pragma unroll
    for (int le=0;le<G;le++){
      float w = wtok[n*E_EXP + e0 + le];
      uint2 wv = *(const uint2*)(gxa + (size_t)le*ND + n*D_MODEL + d0);
      h[le][0] = b2f_hi(wv.x)*h[le][0] + b2f_lo(wv.x);
      h[le][1] = b2f_hi(wv.y)*h[le][1] + b2f_lo(wv.y);
      o0 += w*h[le][0];
      o1 += w*h[le][1];
    }
    float* op = out + n*D_MODEL + d0;
    if (FIRST){ op[0]=o0;  op[1]=o1;  }
    else      { op[0]+=o0; op[1]+=o1; }
  }
}

extern "C" void kernel_launch(void* const* d_in, const int* in_sizes, int n_in,
                              void* d_out, int out_size, void* d_ws, size_t ws_size,
                              hipStream_t stream)
{
  const float* x     = (const float*)d_in[0];
  const float* Wg    = (const float*)d_in[1];
  const float* bg    = (const float*)d_in[2];
  const float* Wv    = (const float*)d_in[3];
  const float* bv    = (const float*)d_in[4];
  const float* Wd    = (const float*)d_in[5];
  const float* bd    = (const float*)d_in[6];
  const float* Wgate = (const float*)d_in[7];
  float* out = (float*)d_out;

  const size_t DD        = (size_t)D_MODEL*D_MODEL;
  const size_t ND        = (size_t)NTOK*D_MODEL;
  const size_t wtok_b    = (size_t)NTOK*E_EXP*4;             // 256 KiB
  const size_t xbf_b     = ND*2;                             // 32 MiB
  const size_t w_per_e   = 3*DD*2;                           // 6 MiB
  const size_t gxa_per_e = ND*4;                             // 64 MiB (u32 xs|aa)
  const size_t st_per_e  = (size_t)B_BATCH*NCHUNK*D_MODEL*4; // 2 MiB

  int G = 1;
  for (int g = 4; g >= 1; g >>= 1){
    size_t need = wtok_b + xbf_b + (size_t)g*(w_per_e + gxa_per_e + 3*st_per_e);
    if (need <= ws_size){ G = g; break; }
  }

  char* wsb = (char*)d_ws;
  size_t off = 0;
  float*          wtok = (float*)(wsb+off);          off += wtok_b;
  unsigned short* xbf  = (unsigned short*)(wsb+off); off += xbf_b;
  unsigned short* Wcat = (unsigned short*)(wsb+off); off += (size_t)G*w_per_e;
  unsigned*       gxa  = (unsigned*)(wsb+off);       off += (size_t)G*gxa_per_e;
  float*          P    = (float*)(wsb+off);          off += (size_t)G*st_per_e;
  float*          U    = (float*)(wsb+off);          off += (size_t)G*st_per_e;
  float*          Hi   = (float*)(wsb+off);

  cvt_bf16<<<(unsigned)(ND/1024), 256, 0, stream>>>(x, xbf);
  router_kernel<<<NTOK/4, 256, 0, stream>>>(x, Wgate, wtok);

  for (int e0=0; e0<E_EXP; e0+=G){
    cvt_w3<<<(unsigned)((size_t)G*3*DD/1024), 256, 0, stream>>>(Wg, Wv, Wd, Wcat, e0);

    dim3 gg(NTOK/BM2, D_MODEL/BN2, G);
    gemm_fused<<<gg, 512, 0, stream>>>(xbf, Wcat, bg, bv, bd, gxa, e0);

    scan_pass1<<<G*B_BATCH*NCHUNK, 512, 0, stream>>>(gxa, P, U);
    scan_pass2<<<G*B_BATCH*D_MODEL/256, 256, 0, stream>>>(P, U, Hi);
    bool first = (e0 == 0);
    if (G==4)      scan_pass3<4,1><<<B_BATCH*NCHUNK, 512, 0, stream>>>(gxa, Hi, wtok, out, e0);
    else if (G==2){
      if (first) scan_pass3<2,1><<<B_BATCH*NCHUNK, 512, 0, stream>>>(gxa, Hi, wtok, out, e0);
      else       scan_pass3<2,0><<<B_BATCH*NCHUNK, 512, 0, stream>>>(gxa, Hi, wtok, out, e0);
    } else {
      if (first) scan_pass3<1,1><<<B_BATCH*NCHUNK, 512, 0, stream>>>(gxa, Hi, wtok, out, e0);
      else       scan_pass3<1,0><<<B_BATCH*NCHUNK, 512, 0, stream>>>(gxa, Hi, wtok, out, e0);
    }
  }
}

// Round 5
// 987.724 us; speedup vs baseline: 1.2142x; 1.2136x over previous
//
#include <hip/hip_runtime.h>

#define E_EXP 4
#define D_MODEL 1024
#define B_BATCH 4
#define S_SEQ 4096
#define NTOK (B_BATCH*S_SEQ)   // 16384
#define CHUNK 32
#define NCHUNK (S_SEQ/CHUNK)   // 128

typedef float f4 __attribute__((ext_vector_type(4)));
typedef float f32x4 __attribute__((ext_vector_type(4)));
typedef short bf16x8 __attribute__((ext_vector_type(8)));

__device__ __forceinline__ unsigned short f2b(float f){
  union{float f;unsigned u;}v; v.f=f;
  unsigned r = v.u + 0x7fffu + ((v.u>>16)&1u);
  return (unsigned short)(r>>16);
}
__device__ __forceinline__ float b2f_lo(unsigned v){ union{unsigned u;float f;}x; x.u=v<<16; return x.f; }
__device__ __forceinline__ float b2f_hi(unsigned v){ union{unsigned u;float f;}x; x.u=v&0xffff0000u; return x.f; }

__device__ __forceinline__ void gload_lds16(const void* g, void* l){
  __builtin_amdgcn_global_load_lds(
      (const __attribute__((address_space(1))) void*)g,
      (__attribute__((address_space(3))) void*)l, 16, 0, 0);
}

// ---------------- fp32 -> bf16 conversion (flat) ----------------
__global__ __launch_bounds__(256) void cvt_bf16(const float* __restrict__ src,
                                                unsigned short* __restrict__ dst)
{
  size_t i = ((size_t)blockIdx.x*256 + threadIdx.x)*4;
  f4 v = *(const f4*)(src + i);
  ushort4 o; o.x=f2b(v[0]); o.y=f2b(v[1]); o.z=f2b(v[2]); o.w=f2b(v[3]);
  *(ushort4*)(dst + i) = o;
}

// Wg/Wv/Wd expert slices -> Wcat[le][3][D][D] bf16
__global__ __launch_bounds__(256) void cvt_w3(const float* __restrict__ Wg,
                                              const float* __restrict__ Wv,
                                              const float* __restrict__ Wd,
                                              unsigned short* __restrict__ Wcat,
                                              int e0)
{
  const size_t DD = (size_t)D_MODEL*D_MODEL;   // 2^20
  size_t i4 = ((size_t)blockIdx.x*256 + threadIdx.x)*4;
  size_t le3m = i4 >> 20;          // / DD
  size_t rem  = i4 & (DD-1);
  int mat = (int)(le3m % 3);
  int le  = (int)(le3m / 3);
  const float* src = (mat==0 ? Wg : (mat==1 ? Wv : Wd)) + (size_t)(e0+le)*DD + rem;
  f4 v = *(const f4*)src;
  ushort4 o; o.x=f2b(v[0]); o.y=f2b(v[1]); o.z=f2b(v[2]); o.w=f2b(v[3]);
  *(ushort4*)(Wcat + le3m*DD + rem) = o;
}

// ---------------- router: top-2 softmax gate weights per token ----------------
__global__ __launch_bounds__(256) void router_kernel(
    const float* __restrict__ x, const float* __restrict__ Wgate,
    float* __restrict__ wtok)
{
  int gtid = blockIdx.x*256 + threadIdx.x;
  int tok  = gtid >> 6;
  int lane = threadIdx.x & 63;
  const float* xr = x + (size_t)tok * D_MODEL;
  float acc0=0.f,acc1=0.f,acc2=0.f,acc3=0.f;
  for (int k=lane;k<D_MODEL;k+=64){
    float xv = xr[k];
    acc0 += xv*Wgate[0*D_MODEL+k];
    acc1 += xv*Wgate[1*D_MODEL+k];
    acc2 += xv*Wgate[2*D_MODEL+k];
    acc3 += xv*Wgate[3*D_MODEL+k];
  }
  #pragma unroll
  for (int off=32;off>0;off>>=1){
    acc0 += __shfl_down(acc0,off);
    acc1 += __shfl_down(acc1,off);
    acc2 += __shfl_down(acc2,off);
    acc3 += __shfl_down(acc3,off);
  }
  if (lane==0){
    float l[4]={acc0,acc1,acc2,acc3};
    int i1=0;
    #pragma unroll
    for(int e=1;e<4;e++) if (l[e]>l[i1]) i1=e;
    int i2=-1;
    #pragma unroll
    for(int e=0;e<4;e++){ if(e==i1) continue; if(i2<0||l[e]>l[i2]) i2=e; }
    float ex = __expf(l[i2]-l[i1]);
    float w1 = 1.f/(1.f+ex);
    float w2 = ex/(1.f+ex);
    float w[4]={0.f,0.f,0.f,0.f};
    w[i1]=w1; w[i2]=w2;
    float* wp = wtok + (size_t)tok*E_EXP;
    wp[0]=w[0]; wp[1]=w[1]; wp[2]=w[2]; wp[3]=w[3];
  }
}

// ---------------- fused 256x256 bf16 MFMA GEMM: g,v,d in one block + act epilogue ----
// Per block: 3 K-loops (mats g,v,d) over the same (m,n) tile. Round-1 WINDOW2
// schedule. Inter-mat carry (g, then xs) goes through a per-expert global tmp
// buffer as packed row-pair u32 (same block writes+reads it one K-loop later:
// mostly L2-resident, 128KB/block). Registers stay at round-1's proven level:
// 128 AGPR acc + ~124 arch VGPR = 256/wave cap at 2 waves/SIMD (8-wave block).
// Round-3/4 lesson: keeping the carry in regs (pk[64]) forces ~316 regs ->
// unavoidable scratch spill (+260MB FETCH/+350MB WRITE); launch_bounds can't fix.
// Output: ONE u32 plane per expert: lo16 = xs bf16, hi16 = aa bf16.
#define BM2 256
#define BN2 256
#define BK2 64
#define NT2 (D_MODEL/BK2)   // 16

__global__ __launch_bounds__(512, 2) void gemm_fused(
    const unsigned short* __restrict__ A,     // xbf [NTOK][D]
    const unsigned short* __restrict__ Wcat,  // [G][3][D][D] bf16
    const float* __restrict__ bg, const float* __restrict__ bv, const float* __restrict__ bd,
    unsigned* __restrict__ gxa,               // [G][NTOK][D] u32 (xs | aa<<16)
    unsigned* tmp,                            // [G][NTOK/2][D] u32 row-pair carry
    int e0)
{
  __shared__ unsigned short sA[2][BM2][BK2];  // 64 KiB
  __shared__ unsigned short sB[2][BN2][BK2];  // 64 KiB
  const size_t DD = (size_t)D_MODEL*D_MODEL;
  const size_t ND = (size_t)NTOK*D_MODEL;

  const int le    = blockIdx.z;
  const int mbase = blockIdx.x*BM2;
  const int nbase = blockIdx.y*BN2;           // y in 0..3
  const int e     = e0 + le;

  const int tid  = threadIdx.x;
  const int wave = tid>>6, lane = tid&63;
  const int wm = wave>>2, wn = wave&3;        // 2M x 4N wave grid; per-wave out 128x64
  const int l15 = lane&15;
  const int l8  = lane>>3;
  const int lc  = (lane&7) ^ l8;              // pre-swizzled logical chunk for staging

  const unsigned short* gA  = A + (size_t)(mbase + wave*8 + l8)*D_MODEL + lc*8;
  const int bBw = (wave>>1)*64 + (wave&1)*8;  // per-wave B dest row base
  const unsigned short* gB0 = Wcat + (size_t)le*3*DD + (size_t)(nbase + bBw + l8)*D_MODEL + lc*8;
  const unsigned short* gB  = gB0;

  // fragment read addressing (swizzle-aware)
  const int arow = wm*128 + l15;
  const int brow = wn*64  + l15;
  const int ach0 = (((lane>>4)    ) ^ (lane&7))*8;   // kk=0 phys chunk, ushort off
  const int ach1 = (((lane>>4) + 4) ^ (lane&7))*8;   // kk=1

  f32x4 acc[8][4];
  bf16x8 af[4][2], bfv[2][2];

#define STAGE_A2(slot,t,mh) do{ \
  gload_lds16(gA + (size_t)((mh)*64)*D_MODEL     + (t)*BK2, &sA[slot][(mh)*64 + wave*8][0]); \
  gload_lds16(gA + (size_t)(128+(mh)*64)*D_MODEL + (t)*BK2, &sA[slot][128+(mh)*64 + wave*8][0]); \
}while(0)
#define STAGE_B2(slot,t,nh) do{ \
  gload_lds16(gB + (size_t)((nh)*32)*D_MODEL    + (t)*BK2, &sB[slot][bBw + (nh)*32][0]); \
  gload_lds16(gB + (size_t)((nh)*32+16)*D_MODEL + (t)*BK2, &sB[slot][bBw + (nh)*32 + 16][0]); \
}while(0)
#define LOAD_A2(slot,mh) do{ \
  _Pragma("unroll") for (int _m=0;_m<4;++_m){ \
    af[_m][0] = *(const bf16x8*)&sA[slot][arow + ((mh)*4+_m)*16][ach0]; \
    af[_m][1] = *(const bf16x8*)&sA[slot][arow + ((mh)*4+_m)*16][ach1]; \
  } \
}while(0)
#define LOAD_B2(slot,nh) do{ \
  _Pragma("unroll") for (int _n=0;_n<2;++_n){ \
    bfv[_n][0] = *(const bf16x8*)&sB[slot][brow + ((nh)*2+_n)*16][ach0]; \
    bfv[_n][1] = *(const bf16x8*)&sB[slot][brow + ((nh)*2+_n)*16][ach1]; \
  } \
}while(0)
#define MQ2(mh,nh) do{ \
  _Pragma("unroll") for (int _m=0;_m<4;++_m) \
  _Pragma("unroll") for (int _n=0;_n<2;++_n) \
  _Pragma("unroll") for (int _k=0;_k<2;++_k) \
    acc[(mh)*4+_m][(nh)*2+_n] = __builtin_amdgcn_mfma_f32_16x16x32_bf16( \
        af[_m][_k], bfv[_n][_k], acc[(mh)*4+_m][(nh)*2+_n], 0,0,0); \
}while(0)
#define KC_LGKM0  asm volatile("s_waitcnt lgkmcnt(0)" ::: "memory")
#define KC_LGKM8  asm volatile("s_waitcnt lgkmcnt(8)" ::: "memory")
#define KC_VM4    asm volatile("s_waitcnt vmcnt(4)" ::: "memory")
#define BAR       __builtin_amdgcn_s_barrier()
#define PRIO1     __builtin_amdgcn_s_setprio(1)
#define PRIO0     __builtin_amdgcn_s_setprio(0)

// Round-1 verified window: quadrant order (0,0),(0,1),(1,1),(1,0); stages:
// ph0: A1+B0(T1)->oslot; ph2: A0(T2)->slot; ph3: B1(T2)->slot + vmcnt(4)
#define WINDOW2(slot,oslot,T1,T2) do{ \
  LOAD_A2(slot,0); LOAD_B2(slot,0); \
  STAGE_A2(oslot,T1,1); STAGE_B2(oslot,T1,0); \
  KC_LGKM8; BAR; KC_LGKM0; \
  PRIO1; MQ2(0,0); PRIO0; BAR; \
  LOAD_B2(slot,1); \
  BAR; KC_LGKM0; \
  PRIO1; MQ2(0,1); PRIO0; BAR; \
  LOAD_A2(slot,1); \
  STAGE_A2(slot,T2,0); \
  BAR; KC_LGKM0; \
  PRIO1; MQ2(1,1); PRIO0; BAR; \
  LOAD_B2(slot,0); \
  STAGE_B2(slot,T2,1); \
  KC_VM4; BAR; KC_LGKM0; \
  PRIO1; MQ2(1,0); PRIO0; BAR; \
}while(0)

#define RUN_MAT() do{ \
  _Pragma("unroll") for (int _i=0;_i<8;_i++) \
    _Pragma("unroll") for (int _j=0;_j<4;_j++) acc[_i][_j] = 0; \
  STAGE_A2(0,0,0); STAGE_A2(0,0,1); STAGE_B2(0,0,0); STAGE_B2(0,0,1); \
  STAGE_A2(1,1,0); STAGE_B2(1,1,1); \
  KC_VM4; BAR; \
  for (int tp=0; tp<NT2/2; ++tp){ \
    int ta = 2*tp+1; \
    int tb = 2*tp+2; if (tb>=NT2) tb -= NT2; \
    int tc = 2*tp+3; if (tc>=NT2) tc -= NT2; \
    WINDOW2(0,1,ta,tb); \
    WINDOW2(1,0,tb,tc); \
  } \
  asm volatile("s_waitcnt vmcnt(0)" ::: "memory"); \
}while(0)

  const int ne = nbase + wn*64;
  const int me = mbase + wm*128;
  unsigned* tmpp = tmp + (size_t)le*(ND/2);   // [NTOK/2][D] u32 row-pair carry

  // ---- mat 0: g -> pack row-pairs to tmp (bf16 round == prior g-plane numerics) ----
  RUN_MAT();
  #pragma unroll
  for (int mi=0;mi<8;mi++)
    #pragma unroll
    for (int j=0;j<2;j++){
      int m0 = me + mi*16 + (lane>>4)*4 + 2*j;          // even
      size_t pr = (size_t)(m0>>1)*D_MODEL;
      #pragma unroll
      for (int ni=0;ni<4;ni++){
        int n = ne + ni*16 + l15;
        tmpp[pr+n] = (unsigned)f2b(acc[mi][ni][2*j]) | ((unsigned)f2b(acc[mi][ni][2*j+1])<<16);
      }
    }

  // ---- mat 1: v -> xs = sigmoid(g+bg)*tanh(v+bv); tmp := xs row-pairs ----
  gB = gB0 + DD;
  RUN_MAT();   // ends vmcnt(0): mat-0 tmp stores drained before reload
  {
    float bgv[4], bvv[4];
    #pragma unroll
    for (int ni=0;ni<4;ni++){
      int n = ne + ni*16 + l15;
      bgv[ni] = bg[(size_t)e*D_MODEL + n];
      bvv[ni] = bv[(size_t)e*D_MODEL + n];
    }
    #pragma unroll
    for (int mi=0;mi<8;mi++)
      #pragma unroll
      for (int j=0;j<2;j++){
        int m0 = me + mi*16 + (lane>>4)*4 + 2*j;
        size_t pr = (size_t)(m0>>1)*D_MODEL;
        #pragma unroll
        for (int ni=0;ni<4;ni++){
          int n = ne + ni*16 + l15;
          unsigned w = tmpp[pr+n];
          float g0 = b2f_lo(w)+bgv[ni], g1 = b2f_hi(w)+bgv[ni];
          float v0 = acc[mi][ni][2*j]+bvv[ni], v1 = acc[mi][ni][2*j+1]+bvv[ni];
          float x0 = (1.f/(1.f+__expf(-g0))) * (1.f - 2.f/(__expf(2.f*v0)+1.f));
          float x1 = (1.f/(1.f+__expf(-g1))) * (1.f - 2.f/(__expf(2.f*v1)+1.f));
          tmpp[pr+n] = (unsigned)f2b(x0) | ((unsigned)f2b(x1)<<16);
        }
      }
  }

  // ---- mat 2: d -> aa = 0.001+0.998*sigmoid(d+bd); store xs|aa u32 plane ----
  gB = gB0 + 2*DD;
  RUN_MAT();   // ends vmcnt(0): mat-1 tmp stores drained before reload
  {
    float bdv[4];
    #pragma unroll
    for (int ni=0;ni<4;ni++) bdv[ni] = bd[(size_t)e*D_MODEL + ne + ni*16 + l15];
    unsigned* outp = gxa + (size_t)le*ND;
    #pragma unroll
    for (int mi=0;mi<8;mi++){
      #pragma unroll
      for (int j=0;j<2;j++){
        int m0 = me + mi*16 + (lane>>4)*4 + 2*j;
        size_t pr  = (size_t)(m0>>1)*D_MODEL;
        size_t ro0 = (size_t)m0*D_MODEL;
        size_t ro1 = ro0 + D_MODEL;
        #pragma unroll
        for (int ni=0;ni<4;ni++){
          int n = ne + ni*16 + l15;
          unsigned w = tmpp[pr+n];                       // xs pair
          float d0v = acc[mi][ni][2*j]   + bdv[ni];
          float d1v = acc[mi][ni][2*j+1] + bdv[ni];
          float a0 = 0.001f + 0.998f/(1.f+__expf(-d0v));
          float a1 = 0.001f + 0.998f/(1.f+__expf(-d1v));
          outp[ro0+n] = (w & 0xffffu) | ((unsigned)f2b(a0)<<16);
          outp[ro1+n] = (w >> 16)     | ((unsigned)f2b(a1)<<16);
        }
      }
    }
  }
}

// ---------------- pass 1 (lean): local chunk scan over packed xs|aa ----------------
__global__ __launch_bounds__(512) void scan_pass1(
    const unsigned* __restrict__ gxa,   // [G][NTOK][D] u32
    float* __restrict__ P, float* __restrict__ U)
{
  const size_t ND = (size_t)NTOK*D_MODEL;
  int blk = blockIdx.x;
  int c  = blk % NCHUNK;
  int b  = (blk / NCHUNK) % B_BATCH;
  int le = blk / (NCHUNK*B_BATCH);
  int d0 = threadIdx.x*2;

  const unsigned* gp = gxa + (size_t)le*ND;
  size_t base = (((size_t)b)*S_SEQ + (size_t)c*CHUNK)*D_MODEL + d0;
  float h0=0.f,h1=0.f,p0=1.f,p1=1.f;
  for (int t=0;t<CHUNK;t++){
    uint2 w = *(const uint2*)(gp + base);
    float x0 = b2f_lo(w.x), a0 = b2f_hi(w.x);
    float x1 = b2f_lo(w.y), a1 = b2f_hi(w.y);
    h0 = a0*h0 + x0; h1 = a1*h1 + x1;
    p0 *= a0; p1 *= a1;
    base += D_MODEL;
  }
  size_t sidx = (((size_t)(le*B_BATCH + b))*NCHUNK + c)*D_MODEL + d0;
  P[sidx]=p0; P[sidx+1]=p1;
  U[sidx]=h0; U[sidx+1]=h1;
}

// ---------------- pass 2: sequential combine over chunks -> Hinit per chunk ----------------
__global__ __launch_bounds__(256) void scan_pass2(
    const float* __restrict__ P, const float* __restrict__ U, float* __restrict__ Hinit)
{
  int ch = blockIdx.x*256 + threadIdx.x;
  int d  = ch & (D_MODEL-1);
  int eb = ch >> 10;
  size_t base = (size_t)eb*NCHUNK*D_MODEL + d;
  float H=0.f;
  for (int c=0;c<NCHUNK;c++){
    size_t idx = base + (size_t)c*D_MODEL;
    Hinit[idx] = H;
    H = P[idx]*H + U[idx];
  }
}

// ---------------- pass 3: re-scan + fused top-2 weighted combine ----------------
template<int G, int FIRST>
__global__ __launch_bounds__(512) void scan_pass3(
    const unsigned* __restrict__ gxa,   // [G][NTOK][D] u32 (xs | aa<<16)
    const float* __restrict__ Hinit, const float* __restrict__ wtok,
    float* __restrict__ out, int e0)
{
  const size_t ND = (size_t)NTOK*D_MODEL;
  int blk = blockIdx.x;
  int c = blk % NCHUNK;
  int b = blk / NCHUNK;
  int d0 = threadIdx.x*2;
  float h[G][2];
  #pragma unroll
  for (int le=0; le<G; le++){
    size_t hi = (((size_t)(le*B_BATCH+b))*NCHUNK + c)*D_MODEL + d0;
    h[le][0]=Hinit[hi]; h[le][1]=Hinit[hi+1];
  }
  int s0 = c*CHUNK;
  for (int t=0;t<CHUNK;t++){
    size_t n = (size_t)b*S_SEQ + s0 + t;
    float o0=0.f, o1=0.f;
    #pragma unroll
    for (int le=0;le<G;le++){
      float w = wtok[n*E_EXP + e0 + le];
      uint2 wv = *(const uint2*)(gxa + (size_t)le*ND + n*D_MODEL + d0);
      h[le][0] = b2f_hi(wv.x)*h[le][0] + b2f_lo(wv.x);
      h[le][1] = b2f_hi(wv.y)*h[le][1] + b2f_lo(wv.y);
      o0 += w*h[le][0];
      o1 += w*h[le][1];
    }
    float* op = out + n*D_MODEL + d0;
    if (FIRST){ op[0]=o0;  op[1]=o1;  }
    else      { op[0]+=o0; op[1]+=o1; }
  }
}

extern "C" void kernel_launch(void* const* d_in, const int* in_sizes, int n_in,
                              void* d_out, int out_size, void* d_ws, size_t ws_size,
                              hipStream_t stream)
{
  const float* x     = (const float*)d_in[0];
  const float* Wg    = (const float*)d_in[1];
  const float* bg    = (const float*)d_in[2];
  const float* Wv    = (const float*)d_in[3];
  const float* bv    = (const float*)d_in[4];
  const float* Wd    = (const float*)d_in[5];
  const float* bd    = (const float*)d_in[6];
  const float* Wgate = (const float*)d_in[7];
  float* out = (float*)d_out;

  const size_t DD        = (size_t)D_MODEL*D_MODEL;
  const size_t ND        = (size_t)NTOK*D_MODEL;
  const size_t wtok_b    = (size_t)NTOK*E_EXP*4;             // 256 KiB
  const size_t xbf_b     = ND*2;                             // 32 MiB
  const size_t w_per_e   = 3*DD*2;                           // 6 MiB
  const size_t gxa_per_e = ND*4;                             // 64 MiB (u32 xs|aa)
  const size_t tmp_per_e = (ND/2)*4;                         // 32 MiB (row-pair carry)
  const size_t st_per_e  = (size_t)B_BATCH*NCHUNK*D_MODEL*4; // 2 MiB

  int G = 1;
  for (int g = 4; g >= 1; g >>= 1){
    size_t need = wtok_b + xbf_b + (size_t)g*(w_per_e + gxa_per_e + tmp_per_e + 3*st_per_e);
    if (need <= ws_size){ G = g; break; }
  }

  char* wsb = (char*)d_ws;
  size_t off = 0;
  float*          wtok = (float*)(wsb+off);          off += wtok_b;
  unsigned short* xbf  = (unsigned short*)(wsb+off); off += xbf_b;
  unsigned short* Wcat = (unsigned short*)(wsb+off); off += (size_t)G*w_per_e;
  unsigned*       gxa  = (unsigned*)(wsb+off);       off += (size_t)G*gxa_per_e;
  unsigned*       tmp  = (unsigned*)(wsb+off);       off += (size_t)G*tmp_per_e;
  float*          P    = (float*)(wsb+off);          off += (size_t)G*st_per_e;
  float*          U    = (float*)(wsb+off);          off += (size_t)G*st_per_e;
  float*          Hi   = (float*)(wsb+off);

  cvt_bf16<<<(unsigned)(ND/1024), 256, 0, stream>>>(x, xbf);
  router_kernel<<<NTOK/4, 256, 0, stream>>>(x, Wgate, wtok);

  for (int e0=0; e0<E_EXP; e0+=G){
    cvt_w3<<<(unsigned)((size_t)G*3*DD/1024), 256, 0, stream>>>(Wg, Wv, Wd, Wcat, e0);

    dim3 gg(NTOK/BM2, D_MODEL/BN2, G);
    gemm_fused<<<gg, 512, 0, stream>>>(xbf, Wcat, bg, bv, bd, gxa, tmp, e0);

    scan_pass1<<<G*B_BATCH*NCHUNK, 512, 0, stream>>>(gxa, P, U);
    scan_pass2<<<G*B_BATCH*D_MODEL/256, 256, 0, stream>>>(P, U, Hi);
    bool first = (e0 == 0);
    if (G==4)      scan_pass3<4,1><<<B_BATCH*NCHUNK, 512, 0, stream>>>(gxa, Hi, wtok, out, e0);
    else if (G==2){
      if (first) scan_pass3<2,1><<<B_BATCH*NCHUNK, 512, 0, stream>>>(gxa, Hi, wtok, out, e0);
      else       scan_pass3<2,0><<<B_BATCH*NCHUNK, 512, 0, stream>>>(gxa, Hi, wtok, out, e0);
    } else {
      if (first) scan_pass3<1,1><<<B_BATCH*NCHUNK, 512, 0, stream>>>(gxa, Hi, wtok, out, e0);
      else       scan_pass3<1,0><<<B_BATCH*NCHUNK, 512, 0, stream>>>(gxa, Hi, wtok, out, e0);
    }
  }
}

// Round 6
// 804.599 us; speedup vs baseline: 1.4905x; 1.2276x over previous
//
#include <hip/hip_runtime.h>

#define E_EXP 4
#define D_MODEL 1024
#define B_BATCH 4
#define S_SEQ 4096
#define NTOK (B_BATCH*S_SEQ)   // 16384
#define CHUNK 32
#define NCHUNK (S_SEQ/CHUNK)   // 128

typedef float f4 __attribute__((ext_vector_type(4)));
typedef float f32x4 __attribute__((ext_vector_type(4)));
typedef short bf16x8 __attribute__((ext_vector_type(8)));

__device__ __forceinline__ unsigned short f2b(float f){
  union{float f;unsigned u;}v; v.f=f;
  unsigned r = v.u + 0x7fffu + ((v.u>>16)&1u);
  return (unsigned short)(r>>16);
}
__device__ __forceinline__ float b2f_lo(unsigned v){ union{unsigned u;float f;}x; x.u=v<<16; return x.f; }
__device__ __forceinline__ float b2f_hi(unsigned v){ union{unsigned u;float f;}x; x.u=v&0xffff0000u; return x.f; }

__device__ __forceinline__ void gload_lds16(const void* g, void* l){
  __builtin_amdgcn_global_load_lds(
      (const __attribute__((address_space(1))) void*)g,
      (__attribute__((address_space(3))) void*)l, 16, 0, 0);
}

// ---------------- fused prep: x -> bf16 AND router top-2 softmax (reads x ONCE) ----
// One wave per token (4 tokens / 256-thr block). Lane l handles cols l*4 + j*256,
// j=0..3: f4 load -> (a) bf16 convert+store, (b) 4 expert-dot accumulation.
__global__ __launch_bounds__(256) void prep(
    const float* __restrict__ x, const float* __restrict__ Wgate,
    unsigned short* __restrict__ xbf, float* __restrict__ wtok)
{
  int tok  = blockIdx.x*4 + (threadIdx.x>>6);
  int lane = threadIdx.x & 63;
  const float* xr = x + (size_t)tok*D_MODEL;
  unsigned short* xb = xbf + (size_t)tok*D_MODEL;
  float acc0=0.f,acc1=0.f,acc2=0.f,acc3=0.f;
  #pragma unroll
  for (int j=0;j<4;j++){
    int k = lane*4 + j*256;
    f4 v  = *(const f4*)(xr + k);
    f4 w0 = *(const f4*)(Wgate + 0*D_MODEL + k);
    f4 w1 = *(const f4*)(Wgate + 1*D_MODEL + k);
    f4 w2 = *(const f4*)(Wgate + 2*D_MODEL + k);
    f4 w3 = *(const f4*)(Wgate + 3*D_MODEL + k);
    #pragma unroll
    for (int q=0;q<4;q++){
      acc0 += v[q]*w0[q];
      acc1 += v[q]*w1[q];
      acc2 += v[q]*w2[q];
      acc3 += v[q]*w3[q];
    }
    ushort4 o; o.x=f2b(v[0]); o.y=f2b(v[1]); o.z=f2b(v[2]); o.w=f2b(v[3]);
    *(ushort4*)(xb + k) = o;
  }
  #pragma unroll
  for (int off=32;off>0;off>>=1){
    acc0 += __shfl_down(acc0,off);
    acc1 += __shfl_down(acc1,off);
    acc2 += __shfl_down(acc2,off);
    acc3 += __shfl_down(acc3,off);
  }
  if (lane==0){
    float l[4]={acc0,acc1,acc2,acc3};
    int i1=0;
    #pragma unroll
    for(int e=1;e<4;e++) if (l[e]>l[i1]) i1=e;
    int i2=-1;
    #pragma unroll
    for(int e=0;e<4;e++){ if(e==i1) continue; if(i2<0||l[e]>l[i2]) i2=e; }
    float ex = __expf(l[i2]-l[i1]);
    float w1 = 1.f/(1.f+ex);
    float w2 = ex/(1.f+ex);
    float w[4]={0.f,0.f,0.f,0.f};
    w[i1]=w1; w[i2]=w2;
    float* wp = wtok + (size_t)tok*E_EXP;
    wp[0]=w[0]; wp[1]=w[1]; wp[2]=w[2]; wp[3]=w[3];
  }
}

// Wg/Wv/Wd expert slices -> Wcat[le][3][D][D] bf16
__global__ __launch_bounds__(256) void cvt_w3(const float* __restrict__ Wg,
                                              const float* __restrict__ Wv,
                                              const float* __restrict__ Wd,
                                              unsigned short* __restrict__ Wcat,
                                              int e0)
{
  const size_t DD = (size_t)D_MODEL*D_MODEL;   // 2^20
  size_t i4 = ((size_t)blockIdx.x*256 + threadIdx.x)*4;
  size_t le3m = i4 >> 20;          // / DD
  size_t rem  = i4 & (DD-1);
  int mat = (int)(le3m % 3);
  int le  = (int)(le3m / 3);
  const float* src = (mat==0 ? Wg : (mat==1 ? Wv : Wd)) + (size_t)(e0+le)*DD + rem;
  f4 v = *(const f4*)src;
  ushort4 o; o.x=f2b(v[0]); o.y=f2b(v[1]); o.z=f2b(v[2]); o.w=f2b(v[3]);
  *(ushort4*)(Wcat + le3m*DD + rem) = o;
}

// ---------------- 256x256 bf16 MFMA GEMM, 8-phase counted-vmcnt schedule ----------------
// (Round-1 verified kernel, best measured: 229 us/dispatch, MfmaUtil 39%.)
// gvd[(le*3+mat)][m][n] = sum_k x[m,k]*W[mat,n,k]   (raw, no bias/activation)
#define BM2 256
#define BN2 256
#define BK2 64
#define NT2 (D_MODEL/BK2)   // 16

__global__ __launch_bounds__(512, 2) void gemm256(
    const unsigned short* __restrict__ A,     // xbf [NTOK][D]
    const unsigned short* __restrict__ Wcat,  // [G][3][D][D] bf16
    unsigned short* __restrict__ gvd)         // [G][3][NTOK][D] bf16 raw
{
  __shared__ unsigned short sA[2][BM2][BK2];  // 64 KiB
  __shared__ unsigned short sB[2][BN2][BK2];  // 64 KiB
  const size_t DD = (size_t)D_MODEL*D_MODEL;
  const size_t ND = (size_t)NTOK*D_MODEL;

  const int le    = blockIdx.z;
  const int mbase = blockIdx.x*BM2;
  const int ntile = blockIdx.y;              // 0..11
  const int mat   = ntile>>2;                // which matrix (g/v/d)
  const int nbase = (ntile&3)*BN2;           // col within matrix

  const int tid  = threadIdx.x;
  const int wave = tid>>6, lane = tid&63;
  const int wm = wave>>2, wn = wave&3;       // 2M x 4N wave grid; per-wave out 128x64
  const int l15 = lane&15;
  const int l8  = lane>>3;
  const int lc  = (lane&7) ^ l8;             // pre-swizzled logical chunk for staging

  const unsigned short* Wmat = Wcat + ((size_t)le*3 + mat)*DD;
  const unsigned short* gA = A + (size_t)(mbase + wave*8 + l8)*D_MODEL + lc*8;
  const int bBw = (wave>>1)*64 + (wave&1)*8; // per-wave B dest row base
  const unsigned short* gB = Wmat + (size_t)(nbase + bBw + l8)*D_MODEL + lc*8;

  // fragment read addressing (swizzle-aware)
  const int arow = wm*128 + l15;
  const int brow = wn*64  + l15;
  const int ach0 = (((lane>>4)    ) ^ (lane&7))*8;   // kk=0 phys chunk, ushort off
  const int ach1 = (((lane>>4) + 4) ^ (lane&7))*8;   // kk=1

  f32x4 acc[8][4];
  #pragma unroll
  for (int i=0;i<8;i++)
    #pragma unroll
    for (int j=0;j<4;j++) acc[i][j] = 0;

  bf16x8 af[4][2], bfv[2][2];

#define STAGE_A2(slot,t,mh) do{ \
  gload_lds16(gA + (size_t)((mh)*64)*D_MODEL     + (t)*BK2, &sA[slot][(mh)*64 + wave*8][0]); \
  gload_lds16(gA + (size_t)(128+(mh)*64)*D_MODEL + (t)*BK2, &sA[slot][128+(mh)*64 + wave*8][0]); \
}while(0)
#define STAGE_B2(slot,t,nh) do{ \
  gload_lds16(gB + (size_t)((nh)*32)*D_MODEL    + (t)*BK2, &sB[slot][bBw + (nh)*32][0]); \
  gload_lds16(gB + (size_t)((nh)*32+16)*D_MODEL + (t)*BK2, &sB[slot][bBw + (nh)*32 + 16][0]); \
}while(0)
#define LOAD_A2(slot,mh) do{ \
  _Pragma("unroll") for (int _m=0;_m<4;++_m){ \
    af[_m][0] = *(const bf16x8*)&sA[slot][arow + ((mh)*4+_m)*16][ach0]; \
    af[_m][1] = *(const bf16x8*)&sA[slot][arow + ((mh)*4+_m)*16][ach1]; \
  } \
}while(0)
#define LOAD_B2(slot,nh) do{ \
  _Pragma("unroll") for (int _n=0;_n<2;++_n){ \
    bfv[_n][0] = *(const bf16x8*)&sB[slot][brow + ((nh)*2+_n)*16][ach0]; \
    bfv[_n][1] = *(const bf16x8*)&sB[slot][brow + ((nh)*2+_n)*16][ach1]; \
  } \
}while(0)
#define MQ2(mh,nh) do{ \
  _Pragma("unroll") for (int _m=0;_m<4;++_m) \
  _Pragma("unroll") for (int _n=0;_n<2;++_n) \
  _Pragma("unroll") for (int _k=0;_k<2;++_k) \
    acc[(mh)*4+_m][(nh)*2+_n] = __builtin_amdgcn_mfma_f32_16x16x32_bf16( \
        af[_m][_k], bfv[_n][_k], acc[(mh)*4+_m][(nh)*2+_n], 0,0,0); \
}while(0)
#define KC_LGKM0  asm volatile("s_waitcnt lgkmcnt(0)" ::: "memory")
#define KC_LGKM8  asm volatile("s_waitcnt lgkmcnt(8)" ::: "memory")
#define KC_VM4    asm volatile("s_waitcnt vmcnt(4)" ::: "memory")
#define BAR       __builtin_amdgcn_s_barrier()
#define PRIO1     __builtin_amdgcn_s_setprio(1)
#define PRIO0     __builtin_amdgcn_s_setprio(0)

// One K-tile window = 4 phases; quadrant order (0,0),(0,1),(1,1),(1,0).
// Stage ledger: o=0 issues A1+B0 of tile T1 (other slot); o=2 issues A0 of T2
// (own slot, A0 last read at o=1); o=3 issues B1 of T2 then vmcnt(4) which
// drains exactly through o=0's issues => tile T1 fully resident before its window.
#define WINDOW2(slot,oslot,T1,T2) do{ \
  LOAD_A2(slot,0); LOAD_B2(slot,0); \
  STAGE_A2(oslot,T1,1); STAGE_B2(oslot,T1,0); \
  KC_LGKM8; BAR; KC_LGKM0; \
  PRIO1; MQ2(0,0); PRIO0; BAR; \
  LOAD_B2(slot,1); \
  BAR; KC_LGKM0; \
  PRIO1; MQ2(0,1); PRIO0; BAR; \
  LOAD_A2(slot,1); \
  STAGE_A2(slot,T2,0); \
  BAR; KC_LGKM0; \
  PRIO1; MQ2(1,1); PRIO0; BAR; \
  LOAD_B2(slot,0); \
  STAGE_B2(slot,T2,1); \
  KC_VM4; BAR; KC_LGKM0; \
  PRIO1; MQ2(1,0); PRIO0; BAR; \
}while(0)

  // prologue: tile 0 fully into slot0; A0+B1 of tile 1 into slot1 (left in flight)
  STAGE_A2(0,0,0); STAGE_A2(0,0,1); STAGE_B2(0,0,0); STAGE_B2(0,0,1);
  STAGE_A2(1,1,0); STAGE_B2(1,1,1);
  KC_VM4; BAR;

  for (int tp=0; tp<NT2/2; ++tp){
    int ta = 2*tp+1;                       // always < NT2
    int tb = 2*tp+2; if (tb>=NT2) tb -= NT2;   // wrapped stages are in-bounds junk
    int tc = 2*tp+3; if (tc>=NT2) tc -= NT2;
    WINDOW2(0,1,ta,tb);
    WINDOW2(1,0,tb,tc);
  }

  asm volatile("s_waitcnt vmcnt(0)" ::: "memory");   // drain tail junk stages before exit

  // epilogue: raw bf16 store (C/D layout col=lane&15, row=(lane>>4)*4+r)
  unsigned short* outp = gvd + ((size_t)le*3 + mat)*ND;
  const int me = mbase + wm*128;
  const int ne = nbase + wn*64;
  #pragma unroll
  for (int mi=0;mi<8;mi++){
    #pragma unroll
    for (int r=0;r<4;r++){
      int m = me + mi*16 + (lane>>4)*4 + r;
      size_t rowoff = (size_t)m*D_MODEL;
      #pragma unroll
      for (int ni=0;ni<4;ni++){
        int n = ne + ni*16 + l15;
        outp[rowoff+n] = f2b(acc[mi][ni][r]);
      }
    }
  }
}

// ---------------- pass 1: bias+activation + local chunk scan; writes xs,aa in place ----------------
__global__ __launch_bounds__(512) void scan_pass1(
    unsigned short* __restrict__ gvd,   // [G][3][NTOK][D]; g-plane becomes xs, d-plane becomes aa
    const float* __restrict__ bg, const float* __restrict__ bv, const float* __restrict__ bd,
    float* __restrict__ P, float* __restrict__ U, int e0)
{
  const size_t ND = (size_t)NTOK*D_MODEL;
  int blk = blockIdx.x;
  int c  = blk % NCHUNK;
  int b  = (blk / NCHUNK) % B_BATCH;
  int le = blk / (NCHUNK*B_BATCH);
  int d0 = threadIdx.x*2;
  int e  = e0 + le;

  float bg0 = bg[(size_t)e*D_MODEL+d0], bg1 = bg[(size_t)e*D_MODEL+d0+1];
  float bv0 = bv[(size_t)e*D_MODEL+d0], bv1 = bv[(size_t)e*D_MODEL+d0+1];
  float bd0 = bd[(size_t)e*D_MODEL+d0], bd1 = bd[(size_t)e*D_MODEL+d0+1];

  unsigned short* gp = gvd + (size_t)le*3*ND;      // g plane (-> xs)
  size_t base = (((size_t)b)*S_SEQ + (size_t)c*CHUNK)*D_MODEL + d0;
  float h0=0.f,h1=0.f,p0=1.f,p1=1.f;
  for (int t=0;t<CHUNK;t++){
    unsigned gw = *(const unsigned*)(gp + base);
    unsigned vw = *(const unsigned*)(gp + ND + base);
    unsigned dw = *(const unsigned*)(gp + 2*ND + base);
    float g0 = b2f_lo(gw)+bg0, g1 = b2f_hi(gw)+bg1;
    float v0 = b2f_lo(vw)+bv0, v1 = b2f_hi(vw)+bv1;
    float dd0 = b2f_lo(dw)+bd0, dd1 = b2f_hi(dw)+bd1;
    float x0 = (1.f/(1.f+__expf(-g0))) * (1.f - 2.f/(__expf(2.f*v0)+1.f));
    float x1 = (1.f/(1.f+__expf(-g1))) * (1.f - 2.f/(__expf(2.f*v1)+1.f));
    float a0 = 0.001f + 0.998f/(1.f+__expf(-dd0));
    float a1 = 0.001f + 0.998f/(1.f+__expf(-dd1));
    h0 = a0*h0 + x0; h1 = a1*h1 + x1;
    p0 *= a0; p1 *= a1;
    unsigned xsw = (unsigned)f2b(x0) | ((unsigned)f2b(x1)<<16);
    unsigned aaw = (unsigned)f2b(a0) | ((unsigned)f2b(a1)<<16);
    *(unsigned*)(gp + base)        = xsw;   // xs over g-plane
    *(unsigned*)(gp + 2*ND + base) = aaw;   // aa over d-plane
    base += D_MODEL;
  }
  size_t sidx = (((size_t)(le*B_BATCH + b))*NCHUNK + c)*D_MODEL + d0;
  P[sidx]=p0; P[sidx+1]=p1;
  U[sidx]=h0; U[sidx+1]=h1;
}

// ---------------- pass 2: sequential combine over chunks -> Hinit per chunk ----------------
__global__ __launch_bounds__(256) void scan_pass2(
    const float* __restrict__ P, const float* __restrict__ U, float* __restrict__ Hinit)
{
  int ch = blockIdx.x*256 + threadIdx.x;
  int d  = ch & (D_MODEL-1);
  int eb = ch >> 10;
  size_t base = (size_t)eb*NCHUNK*D_MODEL + d;
  float H=0.f;
  for (int c=0;c<NCHUNK;c++){
    size_t idx = base + (size_t)c*D_MODEL;
    Hinit[idx] = H;
    H = P[idx]*H + U[idx];
  }
}

// ---------------- pass 3: re-scan + fused top-2 weighted combine ----------------
template<int G, int FIRST>
__global__ __launch_bounds__(512) void scan_pass3(
    const unsigned short* __restrict__ gvd,   // xs = plane le*3, aa = plane le*3+2
    const float* __restrict__ Hinit, const float* __restrict__ wtok,
    float* __restrict__ out, int e0)
{
  const size_t ND = (size_t)NTOK*D_MODEL;
  int blk = blockIdx.x;
  int c = blk % NCHUNK;
  int b = blk / NCHUNK;
  int d0 = threadIdx.x*2;
  float h[G][2];
  #pragma unroll
  for (int le=0; le<G; le++){
    size_t hi = (((size_t)(le*B_BATCH+b))*NCHUNK + c)*D_MODEL + d0;
    h[le][0]=Hinit[hi]; h[le][1]=Hinit[hi+1];
  }
  int s0 = c*CHUNK;
  for (int t=0;t<CHUNK;t++){
    size_t n = (size_t)b*S_SEQ + s0 + t;
    float o0=0.f, o1=0.f;
    #pragma unroll
    for (int le=0;le<G;le++){
      float w = wtok[n*E_EXP + e0 + le];
      size_t idx = (size_t)le*3*ND + n*D_MODEL + d0;
      unsigned xv = *(const unsigned*)(gvd + idx);
      unsigned av = *(const unsigned*)(gvd + 2*ND + idx);
      h[le][0] = b2f_lo(av)*h[le][0] + b2f_lo(xv);
      h[le][1] = b2f_hi(av)*h[le][1] + b2f_hi(xv);
      o0 += w*h[le][0];
      o1 += w*h[le][1];
    }
    float* op = out + n*D_MODEL + d0;
    if (FIRST){ op[0]=o0;  op[1]=o1;  }
    else      { op[0]+=o0; op[1]+=o1; }
  }
}

extern "C" void kernel_launch(void* const* d_in, const int* in_sizes, int n_in,
                              void* d_out, int out_size, void* d_ws, size_t ws_size,
                              hipStream_t stream)
{
  const float* x     = (const float*)d_in[0];
  const float* Wg    = (const float*)d_in[1];
  const float* bg    = (const float*)d_in[2];
  const float* Wv    = (const float*)d_in[3];
  const float* bv    = (const float*)d_in[4];
  const float* Wd    = (const float*)d_in[5];
  const float* bd    = (const float*)d_in[6];
  const float* Wgate = (const float*)d_in[7];
  float* out = (float*)d_out;

  const size_t DD        = (size_t)D_MODEL*D_MODEL;
  const size_t ND        = (size_t)NTOK*D_MODEL;
  const size_t wtok_b    = (size_t)NTOK*E_EXP*4;             // 256 KiB
  const size_t xbf_b     = ND*2;                             // 32 MiB
  const size_t w_per_e   = 3*DD*2;                           // 6 MiB
  const size_t gvd_per_e = 3*ND*2;                           // 96 MiB
  const size_t st_per_e  = (size_t)B_BATCH*NCHUNK*D_MODEL*4; // 2 MiB

  int G = 1;
  for (int g = 4; g >= 1; g >>= 1){
    size_t need = wtok_b + xbf_b + (size_t)g*(w_per_e + gvd_per_e + 3*st_per_e);
    if (need <= ws_size){ G = g; break; }
  }

  char* wsb = (char*)d_ws;
  size_t off = 0;
  float*          wtok = (float*)(wsb+off);          off += wtok_b;
  unsigned short* xbf  = (unsigned short*)(wsb+off); off += xbf_b;
  unsigned short* Wcat = (unsigned short*)(wsb+off); off += (size_t)G*w_per_e;
  unsigned short* gvd  = (unsigned short*)(wsb+off); off += (size_t)G*gvd_per_e;
  float*          P    = (float*)(wsb+off);          off += (size_t)G*st_per_e;
  float*          U    = (float*)(wsb+off);          off += (size_t)G*st_per_e;
  float*          Hi   = (float*)(wsb+off);

  prep<<<NTOK/4, 256, 0, stream>>>(x, Wgate, xbf, wtok);

  for (int e0=0; e0<E_EXP; e0+=G){
    cvt_w3<<<(unsigned)((size_t)G*3*DD/1024), 256, 0, stream>>>(Wg, Wv, Wd, Wcat, e0);

    dim3 gg(NTOK/BM2, 3*D_MODEL/BN2, G);
    gemm256<<<gg, 512, 0, stream>>>(xbf, Wcat, gvd);

    scan_pass1<<<G*B_BATCH*NCHUNK, 512, 0, stream>>>(gvd, bg, bv, bd, P, U, e0);
    scan_pass2<<<G*B_BATCH*D_MODEL/256, 256, 0, stream>>>(P, U, Hi);
    bool first = (e0 == 0);
    if (G==4)      scan_pass3<4,1><<<B_BATCH*NCHUNK, 512, 0, stream>>>(gvd, Hi, wtok, out, e0);
    else if (G==2){
      if (first) scan_pass3<2,1><<<B_BATCH*NCHUNK, 512, 0, stream>>>(gvd, Hi, wtok, out, e0);
      else       scan_pass3<2,0><<<B_BATCH*NCHUNK, 512, 0, stream>>>(gvd, Hi, wtok, out, e0);
    } else {
      if (first) scan_pass3<1,1><<<B_BATCH*NCHUNK, 512, 0, stream>>>(gvd, Hi, wtok, out, e0);
      else       scan_pass3<1,0><<<B_BATCH*NCHUNK, 512, 0, stream>>>(gvd, Hi, wtok, out, e0);
    }
  }
}